// Round 1
// 149.193 us; speedup vs baseline: 1.0327x; 1.0327x over previous
//
#include <hip/hip_runtime.h>
#include <hip/hip_bf16.h>

#define BB 8
#define SS 1024
#define HH 16
#define DD 64
#define DIMM 1024
#define NUNITS (BB * HH)          // 128 independent (b,h) units
#define UNIT_ELEMS (SS * DD)      // 65536 elems per array per unit

typedef __attribute__((ext_vector_type(8))) short short8;
typedef __attribute__((ext_vector_type(4))) float f32x4;
typedef __attribute__((ext_vector_type(16))) float f32x16;
typedef __attribute__((ext_vector_type(2))) unsigned u32x2;
typedef __attribute__((ext_vector_type(4))) unsigned u32x4;

#if __has_builtin(__builtin_amdgcn_exp2f)
#define EXP2F(x) __builtin_amdgcn_exp2f(x)
#else
#define EXP2F(x) exp2f(x)
#endif
#if __has_builtin(__builtin_amdgcn_rcpf)
#define RCPF(x) __builtin_amdgcn_rcpf(x)
#else
#define RCPF(x) (1.0f / (x))
#endif

// RNE float->bf16, finite inputs only
__device__ inline short f2b(float f) {
    unsigned u = __float_as_uint(f);
    u = (u + 0x7FFFu + ((u >> 16) & 1u)) >> 16;
    return (short)u;
}

// v_cvt_pk_bf16_f32: packs (lo, hi) -> bf16x2, RNE (MODE default)
__device__ __forceinline__ unsigned cvtpk_bf16(float lo, float hi) {
    unsigned r;
    asm("v_cvt_pk_bf16_f32 %0, %1, %2" : "=v"(r) : "v"(lo), "v"(hi));
    return r;
}

// async global->LDS, 16B per lane; LDS dest = wave-uniform base + lane*16
__device__ __forceinline__ void gll16(const void* g, void* l) {
    __builtin_amdgcn_global_load_lds(
        (const __attribute__((address_space(1))) void*)g,
        (__attribute__((address_space(3))) void*)l,
        16, 0, 0);
}

// ---------------- Kernel 1: QKV projection (unchanged) ----------------
__global__ __launch_bounds__(256) void qkv_proj(
    const float* __restrict__ x, const float* __restrict__ Wq,
    const float* __restrict__ Wk, const float* __restrict__ Wv,
    const float* __restrict__ bqp, const float* __restrict__ bkp,
    const float* __restrict__ bvp,
    short* __restrict__ Qo, short* __restrict__ Ko, short* __restrict__ Vto,
    int unit0)
{
    __shared__ alignas(16) short wsm[3][64][72];   // bf16 weights
    __shared__ alignas(16) short xs[64][72];
    __shared__ alignas(16) short tr[64][72];       // pivot buffer

    const int t = threadIdx.x;
    const int bid = blockIdx.x;
    const int stg = bid & 3;
    const int ul = bid >> 2;
    const int unit = unit0 + ul;
    const int h = unit & 15;
    const int b = unit >> 4;

    for (int m = 0; m < 3; ++m) {
        const float* src = ((m == 0) ? Wq : (m == 1) ? Wk : Wv) + h * DD * DD;
        for (int i = 0; i < 4; ++i) {
            int g = t + i * 256;
            int e = g >> 4, c = (g & 15) * 4;
            float4 wv = *reinterpret_cast<const float4*>(src + e * DD + c);
            short4 sv; sv.x = f2b(wv.x); sv.y = f2b(wv.y); sv.z = f2b(wv.z); sv.w = f2b(wv.w);
            *reinterpret_cast<short4*>(&wsm[m][e][c]) = sv;
        }
    }

    const int lane = t & 63, w = t >> 6;
    const int l15 = lane & 15, quad = lane >> 4;

    for (int st2 = 0; st2 < 4; ++st2) {
        const int s0 = (stg * 4 + st2) * 64;
        if (st2) __syncthreads();
        for (int i = 0; i < 4; ++i) {
            int g = t + i * 256;
            int r = g >> 4, c = (g & 15) * 4;
            float4 xv = *reinterpret_cast<const float4*>(
                x + ((size_t)(b * SS + s0 + r)) * DIMM + h * DD + c);
            short4 sv; sv.x = f2b(xv.x); sv.y = f2b(xv.y); sv.z = f2b(xv.z); sv.w = f2b(xv.w);
            *reinterpret_cast<short4*>(&xs[r][c]) = sv;
        }
        __syncthreads();

        short8 a0 = *reinterpret_cast<const short8*>(&xs[w * 16 + l15][quad * 8]);
        short8 a1 = *reinterpret_cast<const short8*>(&xs[w * 16 + l15][32 + quad * 8]);

        f32x4 acc[12];
        for (int m = 0; m < 3; ++m)
            for (int et = 0; et < 4; ++et) {
                short8 w0 = *reinterpret_cast<const short8*>(&wsm[m][et * 16 + l15][quad * 8]);
                short8 w1 = *reinterpret_cast<const short8*>(&wsm[m][et * 16 + l15][32 + quad * 8]);
                f32x4 a = {0.f, 0.f, 0.f, 0.f};
                a = __builtin_amdgcn_mfma_f32_16x16x32_bf16(a0, w0, a, 0, 0, 0);
                a = __builtin_amdgcn_mfma_f32_16x16x32_bf16(a1, w1, a, 0, 0, 0);
                acc[m * 4 + et] = a;
            }

        for (int m = 0; m < 3; ++m) {
            if (m) __syncthreads();
            const float* bp = (m == 0) ? bqp : (m == 1) ? bkp : bvp;
            const float scale = (m == 0) ? 0.125f : 1.0f;
            for (int et = 0; et < 4; ++et) {
                float bias = bp[h * DD + et * 16 + l15];
                int e = et * 16 + l15;
                for (int r = 0; r < 4; ++r) {
                    float v = (acc[m * 4 + et][r] + bias) * scale;
                    int srow = w * 16 + quad * 4 + r;
                    if (m == 2) tr[e][srow] = f2b(v);   // V^T
                    else        tr[srow][e] = f2b(v);   // Q,K
                }
            }
            __syncthreads();
            for (int i = 0; i < 2; ++i) {
                int g = t + i * 256;
                int row = g >> 3, col = (g & 7) * 8;
                short8 val = *reinterpret_cast<const short8*>(&tr[row][col]);
                if (m == 0)
                    *reinterpret_cast<short8*>(Qo + ((size_t)ul * SS + s0 + row) * DD + col) = val;
                else if (m == 1)
                    *reinterpret_cast<short8*>(Ko + ((size_t)ul * SS + s0 + row) * DD + col) = val;
                else
                    *reinterpret_cast<short8*>(Vto + ((size_t)ul * DD + row) * SS + s0 + col) = val;
            }
        }
    }
}

// ---------------- Kernel 2: flash attention, 32x32 MFMA + in-register softmax ----------------
// 4 waves x 32 q-rows = 128 q/block. Key tiles of 64, double-buffered LDS via
// global_load_lds with XOR-swizzled source (linear dest), one barrier per tile.
// P redistribution for PV via v_cvt_pk_bf16_f32 + permlane32_swap (no P LDS).
__global__ __launch_bounds__(256, 4) void attn(
    const short* __restrict__ Q, const short* __restrict__ K,
    const short* __restrict__ Vt, float* __restrict__ out, int unit0, int nu)
{
    __shared__ alignas(16) short ksm[2][64][64];   // K tile  [key][d], chunk-swizzled
    __shared__ alignas(16) short vsm[2][64][64];   // Vt tile [d][key], chunk-swizzled
    __shared__ float lsm[4][32];                   // per-wave row sums

    const int t = threadIdx.x;
    const int bid = blockIdx.x;
    int ul, qt;
    if (nu == NUNITS) {   // XCD-aware swizzle
        int xslot = bid & 7;
        int j = bid >> 3;
        ul = xslot * 16 + (j & 15);
        qt = j >> 4;
    } else {
        ul = bid >> 3;
        qt = bid & 7;
    }
    const int unit = unit0 + ul;
    const int h = unit & 15;
    const int b = unit >> 4;
    const int q0 = qt * 128;
    const int lane = t & 63, w = t >> 6;
    const int r5 = lane & 31;          // q column / tile row
    const int hi = lane >> 5;
    const int l7 = lane & 7;
    const int hl4 = (hi ^ l7) << 4;    // swizzled-read byte xor term

    // Q fragments: B-operand, lane holds Q[q0+w*32+r5][ds*16 + hi*8 + jj]
    short8 qb[4];
    {
        const short* qp = Q + ((size_t)ul * SS + q0 + w * 32 + r5) * DD + hi * 8;
#pragma unroll
        for (int ds = 0; ds < 4; ++ds)
            qb[ds] = *reinterpret_cast<const short8*>(qp + ds * 16);
    }

    // staging: wave w covers rows {w*8..w*8+7} and {32+w*8..}; lane -> row w*8+(l>>3),
    // source chunk = (l&7) ^ (l>>3) so that LDS[row][c] = G[row][c ^ (row&7)]
    const int lrow = lane >> 3, lch = (lane & 7) ^ lrow;
    const short* kg = K + (size_t)ul * UNIT_ELEMS + (size_t)(w * 8 + lrow) * DD + lch * 8;
    const short* vg = Vt + ((size_t)ul * DD + w * 8 + lrow) * SS + lch * 8;

    const char* kread0 = (const char*)&ksm[0][0][0] + r5 * 128;
    const char* vread0 = (const char*)&vsm[0][0][0] + r5 * 128;

    f32x16 o0, o1;
#pragma unroll
    for (int i = 0; i < 16; ++i) { o0[i] = 0.f; o1[i] = 0.f; }
    float lsum = 0.f;

    const float L2E = 1.44269504f;
    const float MBIAS = 11.5415603f;   // 8*log2(e): p = exp(s-8)

    // prologue: stage tile 0 into buffer 0
    {
        short* lk = &ksm[0][w * 8][0];
        short* lv = &vsm[0][w * 8][0];
        gll16(kg, lk); gll16(kg + 32 * DD, lk + 32 * 64);
        gll16(vg, lv); gll16(vg + 32 * SS, lv + 32 * 64);
        kg += 64 * DD; vg += 64;
    }

    for (int kt = 0; kt < 16; ++kt) {
        const int cur = kt & 1;
        __syncthreads();   // compiler drains own gll (vmcnt 0) pre-barrier -> tile[cur] ready

        if (kt < 15) {     // issue next tile's loads; overlap with compute below
            const int nxt = cur ^ 1;
            short* lk = &ksm[nxt][w * 8][0];
            short* lv = &vsm[nxt][w * 8][0];
            gll16(kg, lk); gll16(kg + 32 * DD, lk + 32 * 64);
            gll16(vg, lv); gll16(vg + 32 * SS, lv + 32 * 64);
            kg += 64 * DD; vg += 64;
        }

        const char* kb_ = kread0 + cur * 8192;
        const char* vb_ = vread0 + cur * 8192;

        // S^T = mfma(K-frag, Q-frag): c_n[reg] = S^T[key = n*32 + (reg&3)+8*(reg>>2)+4*hi][q = r5]
        f32x16 c0, c1;
#pragma unroll
        for (int i = 0; i < 16; ++i) { c0[i] = 0.f; c1[i] = 0.f; }

        __builtin_amdgcn_s_setprio(1);
#pragma unroll
        for (int ds = 0; ds < 4; ++ds) {
            short8 ka = *reinterpret_cast<const short8*>(kb_ + ((ds << 5) ^ hl4));
            short8 kb = *reinterpret_cast<const short8*>(kb_ + 4096 + ((ds << 5) ^ hl4));
            c0 = __builtin_amdgcn_mfma_f32_32x32x16_bf16(ka, qb[ds], c0, 0, 0, 0);
            c1 = __builtin_amdgcn_mfma_f32_32x32x16_bf16(kb, qb[ds], c1, 0, 0, 0);
        }
        __builtin_amdgcn_s_setprio(0);

#pragma unroll
        for (int n = 0; n < 2; ++n) {
            f32x16 c = n ? c1 : c0;
            float p[16];
#pragma unroll
            for (int r = 0; r < 16; ++r)
                p[r] = EXP2F(fmaf(c[r], L2E, -MBIAS));
            lsum += ((((p[0] + p[1]) + (p[2] + p[3])) + ((p[4] + p[5]) + (p[6] + p[7])))
                   + (((p[8] + p[9]) + (p[10] + p[11])) + ((p[12] + p[13]) + (p[14] + p[15]))));

#pragma unroll
            for (int bb2 = 0; bb2 < 2; ++bb2) {
                unsigned u0 = cvtpk_bf16(p[8 * bb2 + 0], p[8 * bb2 + 1]);
                unsigned u1 = cvtpk_bf16(p[8 * bb2 + 2], p[8 * bb2 + 3]);
                unsigned v0 = cvtpk_bf16(p[8 * bb2 + 4], p[8 * bb2 + 5]);
                unsigned v1 = cvtpk_bf16(p[8 * bb2 + 6], p[8 * bb2 + 7]);
                unsigned w0, w1c, w2, w3;
#if __has_builtin(__builtin_amdgcn_permlane32_swap)
                u32x2 r0 = __builtin_amdgcn_permlane32_swap(u0, v0, false, false);
                u32x2 r1 = __builtin_amdgcn_permlane32_swap(u1, v1, false, false);
                w0 = r0[0]; w2 = r0[1]; w1c = r1[0]; w3 = r1[1];
#else
                unsigned u0s = __shfl_xor(u0, 32), v0s = __shfl_xor(v0, 32);
                unsigned u1s = __shfl_xor(u1, 32), v1s = __shfl_xor(v1, 32);
                w0 = hi ? v0s : u0;  w2 = hi ? v0 : u0s;
                w1c = hi ? v1s : u1; w3 = hi ? v1 : u1s;
#endif
                u32x4 aw; aw[0] = w0; aw[1] = w1c; aw[2] = w2; aw[3] = w3;
                short8 af = __builtin_bit_cast(short8, aw);

                const int ks = n * 2 + bb2;
                short8 va = *reinterpret_cast<const short8*>(vb_ + ((ks << 5) ^ hl4));
                short8 vb2 = *reinterpret_cast<const short8*>(vb_ + 4096 + ((ks << 5) ^ hl4));
                __builtin_amdgcn_s_setprio(1);
                o0 = __builtin_amdgcn_mfma_f32_32x32x16_bf16(af, va, o0, 0, 0, 0);
                o1 = __builtin_amdgcn_mfma_f32_32x32x16_bf16(af, vb2, o1, 0, 0, 0);
                __builtin_amdgcn_s_setprio(0);
            }
        }
    }

    // row sums: lane and lane^32 hold complementary key-halves for q = r5
    float lt = lsum + __shfl_xor(lsum, 32);
    if (lane < 32) lsm[w][lane] = lt;
    // same-wave LDS write->read; compiler inserts lgkmcnt wait

#pragma unroll
    for (int reg = 0; reg < 16; ++reg) {
        const int row = (reg & 3) + 8 * (reg >> 2) + 4 * hi;
        float rin = RCPF(lsm[w][row]);
        float* op = out + ((size_t)(b * SS + q0 + w * 32 + row)) * DIMM + h * DD + r5;
        op[0]  = o0[reg] * rin;
        op[32] = o1[reg] * rin;
    }
}

extern "C" void kernel_launch(void* const* d_in, const int* in_sizes, int n_in,
                              void* d_out, int out_size, void* d_ws, size_t ws_size,
                              hipStream_t stream) {
    const float* x   = (const float*)d_in[0];
    const float* Wq  = (const float*)d_in[1];
    const float* Wk  = (const float*)d_in[2];
    const float* Wv  = (const float*)d_in[3];
    const float* bqp = (const float*)d_in[4];
    const float* bkp = (const float*)d_in[5];
    const float* bvp = (const float*)d_in[6];
    float* out = (float*)d_out;

    const size_t unit_bytes = 3ULL * UNIT_ELEMS * sizeof(short);  // 384 KB / unit
    int U = (int)(ws_size / unit_bytes);
    if (U < 1) U = 1;
    if (U > NUNITS) U = NUNITS;

    short* Qw  = (short*)d_ws;
    short* Kw  = Qw + (size_t)U * UNIT_ELEMS;
    short* Vtw = Kw + (size_t)U * UNIT_ELEMS;

    for (int u0 = 0; u0 < NUNITS; u0 += U) {
        int nu = NUNITS - u0 < U ? NUNITS - u0 : U;
        qkv_proj<<<dim3(nu * 4), dim3(256), 0, stream>>>(
            x, Wq, Wk, Wv, bqp, bkp, bvp, Qw, Kw, Vtw, u0);
        attn<<<dim3(nu * 8), dim3(256), 0, stream>>>(Qw, Kw, Vtw, out, u0, nu);
    }
}

// Round 2
// 143.014 us; speedup vs baseline: 1.0773x; 1.0432x over previous
//
#include <hip/hip_runtime.h>
#include <hip/hip_bf16.h>

#define BB 8
#define SS 1024
#define HH 16
#define DD 64
#define DIMM 1024
#define NUNITS (BB * HH)          // 128 independent (b,h) units
#define UNIT_ELEMS (SS * DD)      // 65536 elems per array per unit

typedef __attribute__((ext_vector_type(8))) short short8;
typedef __attribute__((ext_vector_type(4))) float f32x4;
typedef __attribute__((ext_vector_type(16))) float f32x16;
typedef __attribute__((ext_vector_type(2))) unsigned u32x2;
typedef __attribute__((ext_vector_type(4))) unsigned u32x4;

#if __has_builtin(__builtin_amdgcn_exp2f)
#define EXP2F(x) __builtin_amdgcn_exp2f(x)
#else
#define EXP2F(x) exp2f(x)
#endif
#if __has_builtin(__builtin_amdgcn_rcpf)
#define RCPF(x) __builtin_amdgcn_rcpf(x)
#else
#define RCPF(x) (1.0f / (x))
#endif

// RNE float->bf16, finite inputs only
__device__ inline short f2b(float f) {
    unsigned u = __float_as_uint(f);
    u = (u + 0x7FFFu + ((u >> 16) & 1u)) >> 16;
    return (short)u;
}
// pack two fp32 -> bf16x2 (lo, hi), RNE
__device__ inline unsigned pk2(float lo, float hi) {
    unsigned a = __float_as_uint(lo), b = __float_as_uint(hi);
    a = (a + 0x7FFFu + ((a >> 16) & 1u)) >> 16;
    b = (b + 0x7FFFu + ((b >> 16) & 1u)) & 0xFFFF0000u;
    return a | b;
}

// v_cvt_pk_bf16_f32: packs (lo, hi) -> bf16x2, RNE
__device__ __forceinline__ unsigned cvtpk_bf16(float lo, float hi) {
    unsigned r;
    asm("v_cvt_pk_bf16_f32 %0, %1, %2" : "=v"(r) : "v"(lo), "v"(hi));
    return r;
}

// exchange lane<32 / lane>=32 halves of two words
__device__ __forceinline__ u32x2 plswap(unsigned a, unsigned b, int hi) {
#if __has_builtin(__builtin_amdgcn_permlane32_swap)
    u32x2 r = __builtin_amdgcn_permlane32_swap(a, b, false, false);
    return r;
#else
    unsigned as = __shfl_xor(a, 32), bs = __shfl_xor(b, 32);
    u32x2 r; r[0] = hi ? bs : a; r[1] = hi ? b : as;
    return r;
#endif
}

// async global->LDS, 16B per lane; LDS dest = wave-uniform base + lane*16
__device__ __forceinline__ void gll16(const void* g, void* l) {
    __builtin_amdgcn_global_load_lds(
        (const __attribute__((address_space(1))) void*)g,
        (__attribute__((address_space(3))) void*)l,
        16, 0, 0);
}

// ---------------- Kernel 1: QKV projection (32x32 MFMA, 2 barriers/tile) ----------------
// grid = nu*4 blocks, 256 thr (4 waves). Block covers 256 s-rows (4 tiles of 64).
// Wave (w&1, w>>1) owns the (s-half, e-half) quadrant for all 3 projections.
// Wq/bq pre-scaled by 0.125 (exact pow2 -> bit-identical to post-scaling).
// Outputs unchanged: Q,K [ul][s][d] bf16 (Q pre-scaled), Vt [ul][d][s] bf16.
__global__ __launch_bounds__(256) void qkv_proj(
    const float* __restrict__ x, const float* __restrict__ Wq,
    const float* __restrict__ Wk, const float* __restrict__ Wv,
    const float* __restrict__ bqp, const float* __restrict__ bkp,
    const float* __restrict__ bvp,
    short* __restrict__ Qo, short* __restrict__ Ko, short* __restrict__ Vto,
    int unit0)
{
    __shared__ alignas(16) short wsm[3][64][72];   // bf16 weights [e][d]
    __shared__ alignas(16) short xs[64][72];       // x tile [s][d]
    __shared__ alignas(16) short trq[64][72];      // Q pivot [s][e]
    __shared__ alignas(16) short trk[64][72];      // K pivot [s][e]
    __shared__ alignas(16) short trv[64][72];      // V pivot [e][s]

    const int t = threadIdx.x;
    const int bid = blockIdx.x;
    const int stg = bid & 3;
    const int ul = bid >> 2;
    const int unit = unit0 + ul;
    const int h = unit & 15;
    const int b = unit >> 4;

    const int lane = t & 63, w = t >> 6;
    const int l31 = lane & 31, hi = lane >> 5;
    const int shalf = w & 1, ehalf = w >> 1;
    const int ecol = ehalf * 32 + l31;

    // stage W fp32 -> bf16 once (Wq scaled by 0.125)
    for (int m = 0; m < 3; ++m) {
        const float* src = ((m == 0) ? Wq : (m == 1) ? Wk : Wv) + h * DD * DD;
        const float ws = (m == 0) ? 0.125f : 1.0f;
        for (int i = 0; i < 4; ++i) {
            int g = t + i * 256;
            int e = g >> 4, c = (g & 15) * 4;
            float4 wv4 = *reinterpret_cast<const float4*>(src + e * DD + c);
            u32x2 pk; pk[0] = pk2(wv4.x * ws, wv4.y * ws);
            pk[1] = pk2(wv4.z * ws, wv4.w * ws);
            *reinterpret_cast<u32x2*>(&wsm[m][e][c]) = pk;
        }
    }
    // hoisted per-lane biases (e = ecol)
    const float bq_ = bqp[h * DD + ecol] * 0.125f;
    const float bk_ = bkp[h * DD + ecol];
    const float bv_ = bvp[h * DD + ecol];

    f32x16 zv;
#pragma unroll
    for (int i = 0; i < 16; ++i) zv[i] = 0.f;

    for (int st = 0; st < 4; ++st) {
        const int s0 = (stg * 4 + st) * 64;
        // stage x tile fp32 -> bf16
        for (int i = 0; i < 4; ++i) {
            int g = t + i * 256;
            int r = g >> 4, c = (g & 15) * 4;
            float4 xv = *reinterpret_cast<const float4*>(
                x + ((size_t)(b * SS + s0 + r)) * DIMM + h * DD + c);
            u32x2 pk; pk[0] = pk2(xv.x, xv.y); pk[1] = pk2(xv.z, xv.w);
            *reinterpret_cast<u32x2*>(&xs[r][c]) = pk;
        }
        __syncthreads();   // sync_A: xs staged (and W on st==0); prev flush done

        // A-frags (shared across the 3 projections)
        short8 a[4];
#pragma unroll
        for (int ks = 0; ks < 4; ++ks)
            a[ks] = *reinterpret_cast<const short8*>(&xs[shalf * 32 + l31][ks * 16 + hi * 8]);

        f32x16 cm[3];
#pragma unroll
        for (int m = 0; m < 3; ++m) {
            short8 wb0 = *reinterpret_cast<const short8*>(&wsm[m][ecol][hi * 8]);
            f32x16 c = __builtin_amdgcn_mfma_f32_32x32x16_bf16(a[0], wb0, zv, 0, 0, 0);
#pragma unroll
            for (int ks = 1; ks < 4; ++ks) {
                short8 wb = *reinterpret_cast<const short8*>(&wsm[m][ecol][ks * 16 + hi * 8]);
                c = __builtin_amdgcn_mfma_f32_32x32x16_bf16(a[ks], wb, c, 0, 0, 0);
            }
            cm[m] = c;
        }

        // pivots: Q,K scalar [s][e]; V vectorized [e][s] (consecutive regs = consecutive s)
#pragma unroll
        for (int reg = 0; reg < 16; ++reg) {
            int srow = shalf * 32 + (reg & 3) + 8 * (reg >> 2) + 4 * hi;
            trq[srow][ecol] = f2b(cm[0][reg] + bq_);
            trk[srow][ecol] = f2b(cm[1][reg] + bk_);
        }
#pragma unroll
        for (int rq = 0; rq < 4; ++rq) {
            int sbase = shalf * 32 + 4 * hi + 8 * rq;
            u32x2 pk;
            pk[0] = pk2(cm[2][4 * rq + 0] + bv_, cm[2][4 * rq + 1] + bv_);
            pk[1] = pk2(cm[2][4 * rq + 2] + bv_, cm[2][4 * rq + 3] + bv_);
            *reinterpret_cast<u32x2*>(&trv[ecol][sbase]) = pk;
        }
        __syncthreads();   // sync_B: pivots written

        // flush: 2 b128 per thread per array, fully coalesced global stores
#pragma unroll
        for (int i = 0; i < 2; ++i) {
            int cidx = t + i * 256;
            int row = cidx >> 3, col8 = (cidx & 7) * 8;
            short8 vq = *reinterpret_cast<const short8*>(&trq[row][col8]);
            short8 vk = *reinterpret_cast<const short8*>(&trk[row][col8]);
            short8 vv = *reinterpret_cast<const short8*>(&trv[row][col8]);
            *reinterpret_cast<short8*>(Qo + ((size_t)ul * SS + s0 + row) * DD + col8) = vq;
            *reinterpret_cast<short8*>(Ko + ((size_t)ul * SS + s0 + row) * DD + col8) = vk;
            *reinterpret_cast<short8*>(Vto + ((size_t)ul * DD + row) * SS + s0 + col8) = vv;
        }
        // next iteration's sync_A orders flush-reads vs next pivot-writes,
        // and this tile's xs reads (pre-sync_B) vs next stage-x writes.
    }
}

// ---------------- Kernel 2: flash attention, 32x32 MFMA + in-register softmax ----------------
__global__ __launch_bounds__(256, 4) void attn(
    const short* __restrict__ Q, const short* __restrict__ K,
    const short* __restrict__ Vt, float* __restrict__ out, int unit0, int nu)
{
    __shared__ alignas(16) short ksm[2][64][64];   // K tile  [key][d], chunk-swizzled
    __shared__ alignas(16) short vsm[2][64][64];   // Vt tile [d][key], chunk-swizzled
    __shared__ float lsm[4][32];                   // per-wave row sums

    const int t = threadIdx.x;
    const int bid = blockIdx.x;
    int ul, qt;
    if (nu == NUNITS) {   // XCD-aware swizzle
        int xslot = bid & 7;
        int j = bid >> 3;
        ul = xslot * 16 + (j & 15);
        qt = j >> 4;
    } else {
        ul = bid >> 3;
        qt = bid & 7;
    }
    const int unit = unit0 + ul;
    const int h = unit & 15;
    const int b = unit >> 4;
    const int q0 = qt * 128;
    const int lane = t & 63, w = t >> 6;
    const int r5 = lane & 31;
    const int hi = lane >> 5;
    const int l7 = lane & 7;
    const int hl4 = (hi ^ l7) << 4;    // swizzled-read byte xor term

    short8 qb[4];
    {
        const short* qp = Q + ((size_t)ul * SS + q0 + w * 32 + r5) * DD + hi * 8;
#pragma unroll
        for (int ds = 0; ds < 4; ++ds)
            qb[ds] = *reinterpret_cast<const short8*>(qp + ds * 16);
    }

    const int lrow = lane >> 3, lch = (lane & 7) ^ lrow;
    const short* kg = K + (size_t)ul * UNIT_ELEMS + (size_t)(w * 8 + lrow) * DD + lch * 8;
    const short* vg = Vt + ((size_t)ul * DD + w * 8 + lrow) * SS + lch * 8;

    const char* kread0 = (const char*)&ksm[0][0][0] + r5 * 128;
    const char* vread0 = (const char*)&vsm[0][0][0] + r5 * 128;

    f32x16 zv;
#pragma unroll
    for (int i = 0; i < 16; ++i) zv[i] = 0.f;
    f32x16 o0 = zv, o1 = zv;
    float lsum = 0.f;

    const float L2E = 1.44269504f;
    const float MBIAS = 11.5415603f;   // 8*log2(e): p = exp(s-8)

    {
        short* lk = &ksm[0][w * 8][0];
        short* lv = &vsm[0][w * 8][0];
        gll16(kg, lk); gll16(kg + 32 * DD, lk + 32 * 64);
        gll16(vg, lv); gll16(vg + 32 * SS, lv + 32 * 64);
        kg += 64 * DD; vg += 64;
    }

// softmax + PV for one 32-key block held in CV (in place, no copy)
#define SMPV(CV, NOFF) do {                                                      \
    float p_[16];                                                                \
    _Pragma("unroll")                                                            \
    for (int r_ = 0; r_ < 16; ++r_) p_[r_] = EXP2F(fmaf(CV[r_], L2E, -MBIAS));   \
    lsum += ((((p_[0]+p_[1])+(p_[2]+p_[3]))+((p_[4]+p_[5])+(p_[6]+p_[7])))       \
           +(((p_[8]+p_[9])+(p_[10]+p_[11]))+((p_[12]+p_[13])+(p_[14]+p_[15])))); \
    _Pragma("unroll")                                                            \
    for (int b2_ = 0; b2_ < 2; ++b2_) {                                          \
        unsigned u0_ = cvtpk_bf16(p_[8*b2_+0], p_[8*b2_+1]);                     \
        unsigned u1_ = cvtpk_bf16(p_[8*b2_+2], p_[8*b2_+3]);                     \
        unsigned v0_ = cvtpk_bf16(p_[8*b2_+4], p_[8*b2_+5]);                     \
        unsigned v1_ = cvtpk_bf16(p_[8*b2_+6], p_[8*b2_+7]);                     \
        u32x2 r0_ = plswap(u0_, v0_, hi);                                        \
        u32x2 r1_ = plswap(u1_, v1_, hi);                                        \
        u32x4 aw_; aw_[0] = r0_[0]; aw_[1] = r1_[0]; aw_[2] = r0_[1]; aw_[3] = r1_[1]; \
        short8 af_ = __builtin_bit_cast(short8, aw_);                            \
        const int ks_ = (NOFF) * 2 + b2_;                                        \
        short8 va_ = *reinterpret_cast<const short8*>(vb_ + ((ks_ << 5) ^ hl4)); \
        short8 vb2_ = *reinterpret_cast<const short8*>(vb_ + 4096 + ((ks_ << 5) ^ hl4)); \
        __builtin_amdgcn_s_setprio(1);                                           \
        o0 = __builtin_amdgcn_mfma_f32_32x32x16_bf16(af_, va_, o0, 0, 0, 0);     \
        o1 = __builtin_amdgcn_mfma_f32_32x32x16_bf16(af_, vb2_, o1, 0, 0, 0);    \
        __builtin_amdgcn_s_setprio(0);                                           \
    }                                                                            \
} while (0)

    for (int kt = 0; kt < 16; ++kt) {
        const int cur = kt & 1;
        __syncthreads();   // compiler drains own gll (vmcnt 0) pre-barrier -> tile[cur] ready

        if (kt < 15) {     // prefetch next tile; lands during compute below
            const int nxt = cur ^ 1;
            short* lk = &ksm[nxt][w * 8][0];
            short* lv = &vsm[nxt][w * 8][0];
            gll16(kg, lk); gll16(kg + 32 * DD, lk + 32 * 64);
            gll16(vg, lv); gll16(vg + 32 * SS, lv + 32 * 64);
            kg += 64 * DD; vg += 64;
        }

        const char* kb_ = kread0 + cur * 8192;
        const char* vb_ = vread0 + cur * 8192;

        // S^T = mfma(K-frag, Q-frag); first MFMA consumes persistent zero vector
        f32x16 c0, c1;
        __builtin_amdgcn_s_setprio(1);
        {
            short8 ka = *reinterpret_cast<const short8*>(kb_ + hl4);
            short8 kb = *reinterpret_cast<const short8*>(kb_ + 4096 + hl4);
            c0 = __builtin_amdgcn_mfma_f32_32x32x16_bf16(ka, qb[0], zv, 0, 0, 0);
            c1 = __builtin_amdgcn_mfma_f32_32x32x16_bf16(kb, qb[0], zv, 0, 0, 0);
        }
#pragma unroll
        for (int ds = 1; ds < 4; ++ds) {
            short8 ka = *reinterpret_cast<const short8*>(kb_ + ((ds << 5) ^ hl4));
            short8 kb = *reinterpret_cast<const short8*>(kb_ + 4096 + ((ds << 5) ^ hl4));
            c0 = __builtin_amdgcn_mfma_f32_32x32x16_bf16(ka, qb[ds], c0, 0, 0, 0);
            c1 = __builtin_amdgcn_mfma_f32_32x32x16_bf16(kb, qb[ds], c1, 0, 0, 0);
        }
        __builtin_amdgcn_s_setprio(0);

        SMPV(c0, 0);
        SMPV(c1, 1);
    }
#undef SMPV

    // row sums: lane and lane^32 hold complementary key-halves for q = r5
    float lt = lsum + __shfl_xor(lsum, 32);
    if (lane < 32) lsm[w][lane] = lt;
    // same-wave LDS write->read; compiler inserts lgkmcnt wait

#pragma unroll
    for (int reg = 0; reg < 16; ++reg) {
        const int row = (reg & 3) + 8 * (reg >> 2) + 4 * hi;
        float rin = RCPF(lsm[w][row]);
        float* op = out + ((size_t)(b * SS + q0 + w * 32 + row)) * DIMM + h * DD + r5;
        op[0]  = o0[reg] * rin;
        op[32] = o1[reg] * rin;
    }
}

extern "C" void kernel_launch(void* const* d_in, const int* in_sizes, int n_in,
                              void* d_out, int out_size, void* d_ws, size_t ws_size,
                              hipStream_t stream) {
    const float* x   = (const float*)d_in[0];
    const float* Wq  = (const float*)d_in[1];
    const float* Wk  = (const float*)d_in[2];
    const float* Wv  = (const float*)d_in[3];
    const float* bqp = (const float*)d_in[4];
    const float* bkp = (const float*)d_in[5];
    const float* bvp = (const float*)d_in[6];
    float* out = (float*)d_out;

    const size_t unit_bytes = 3ULL * UNIT_ELEMS * sizeof(short);  // 384 KB / unit
    int U = (int)(ws_size / unit_bytes);
    if (U < 1) U = 1;
    if (U > NUNITS) U = NUNITS;

    short* Qw  = (short*)d_ws;
    short* Kw  = Qw + (size_t)U * UNIT_ELEMS;
    short* Vtw = Kw + (size_t)U * UNIT_ELEMS;

    for (int u0 = 0; u0 < NUNITS; u0 += U) {
        int nu = NUNITS - u0 < U ? NUNITS - u0 : U;
        qkv_proj<<<dim3(nu * 4), dim3(256), 0, stream>>>(
            x, Wq, Wk, Wv, bqp, bkp, bvp, Qw, Kw, Vtw, u0);
        attn<<<dim3(nu * 8), dim3(256), 0, stream>>>(Qw, Kw, Vtw, out, u0, nu);
    }
}